// Round 7
// baseline (153.071 us; speedup 1.0000x reference)
//
#include <hip/hip_runtime.h>

typedef float f4 __attribute__((ext_vector_type(4)));

#define BB 1024
#define SS 192
#define DD 512
#define NUM_LAYERS 3
#define LN_EPS 1e-5f
#define NROWS (BB * SS)
#define CONTENT_BLOCKS 2048
#define NWAVES (CONTENT_BLOCKS * 4)

// Phase A: one pair of blocks per batch row b. Compute start[b] via ballot
// (self-contained), publish it, then dense zero-store of the padded prefix.
// Chip-wide this is a pure-write burst at fill rate.
__global__ __launch_bounds__(256) void zerofill_kernel(
    const int* __restrict__ mask,
    int* __restrict__ start,
    float* __restrict__ out)
{
    const int b = blockIdx.x >> 1;
    const int half = blockIdx.x & 1;
    const int tid = threadIdx.x;
    const int lane = tid & 63;

    const int* m = mask + b * SS;
    const unsigned long long b0 = __ballot(m[lane] > 0);
    const unsigned long long b1 = __ballot(m[lane + 64] > 0);
    const unsigned long long b2 = __ballot(m[lane + 128] > 0);
    int st;
    if (b0)      st = __ffsll(b0) - 1;
    else if (b1) st = 64 + __ffsll(b1) - 1;
    else if (b2) st = 128 + __ffsll(b2) - 1;
    else         st = SS;

    if (half == 0 && tid == 0) start[b] = st;

    f4* o4 = reinterpret_cast<f4*>(out + (size_t)b * SS * DD);
    const int nf4 = st * (DD / 4);
    const f4 z = {0.f, 0.f, 0.f, 0.f};
    for (int i = half * 256 + tid; i < nf4; i += 512)
        o4[i] = z;                                // independent dense stores
}

// Phase B prep: add_tab[pos] = item_pos[pos/3] + layer[pos%3] + decay[pos/3]
__global__ __launch_bounds__(128) void prep_kernel(
    const float* __restrict__ item_pos,
    const float* __restrict__ layer_emb,
    const float* __restrict__ decay,
    float* __restrict__ add_tab)
{
    const int p = blockIdx.x;
    const int t = threadIdx.x;                    // 0..127 = DD/4
    const int item = p / NUM_LAYERS;
    const int layer = p - item * NUM_LAYERS;
    const f4 iv = reinterpret_cast<const f4*>(item_pos + item * DD)[t];
    const f4 lv = reinterpret_cast<const f4*>(layer_emb + layer * DD)[t];
    const f4 dv = reinterpret_cast<const f4*>(decay + item * DD)[t];
    reinterpret_cast<f4*>(add_tab + p * DD)[t] = iv + lv + dv;
}

// DPP-based wave64 all-reduce (sum).
__device__ __forceinline__ float wave_allreduce(float v, int xaddr32) {
    v += __uint_as_float((unsigned)__builtin_amdgcn_update_dpp(
            0, (int)__float_as_uint(v), 0xB1, 0xF, 0xF, true));   // xor1
    v += __uint_as_float((unsigned)__builtin_amdgcn_update_dpp(
            0, (int)__float_as_uint(v), 0x4E, 0xF, 0xF, true));   // xor2
    v += __uint_as_float((unsigned)__builtin_amdgcn_update_dpp(
            0, (int)__float_as_uint(v), 0x141, 0xF, 0xF, true));  // row_half_mirror
    v += __uint_as_float((unsigned)__builtin_amdgcn_update_dpp(
            0, (int)__float_as_uint(v), 0x140, 0xF, 0xF, true));  // row_mirror
    v += __uint_as_float((unsigned)__builtin_amdgcn_ds_swizzle(
            (int)__float_as_uint(v), 0x401f));                    // xor16
    v += __uint_as_float((unsigned)__builtin_amdgcn_ds_bpermute(
            xaddr32, (int)__float_as_uint(v)));                   // xor32
    return v;
}

// Phase C: content rows only. Padded rows cost ~a branch (no store -- zeros
// already written by phase A). Content rows are read+write 1:1, copy-shaped.
__global__ __launch_bounds__(256) void content_kernel(
    const float* __restrict__ tok,
    const float* __restrict__ add_tab,
    const float* __restrict__ lnw,
    const float* __restrict__ lnb,
    const int* __restrict__ start,
    float* __restrict__ out)
{
    const int wid = threadIdx.x >> 6;
    const int lane = threadIdx.x & 63;
    const int l0 = lane;
    const int l1 = lane + 64;
    const int xaddr32 = (lane ^ 32) << 2;

    const f4 w0 = reinterpret_cast<const f4*>(lnw)[l0];
    const f4 w1 = reinterpret_cast<const f4*>(lnw)[l1];
    const f4 c0 = reinterpret_cast<const f4*>(lnb)[l0];
    const f4 c1 = reinterpret_cast<const f4*>(lnb)[l1];

    const int wave = blockIdx.x * 4 + wid;

    #pragma unroll 1
    for (int row = wave; row < NROWS; row += NWAVES) {
        const int b = row / SS;
        const int s = row - b * SS;
        const int st = start[b];                  // 4KB array, L1-resident

        if (s < st) continue;                     // padded: nothing to do

        const int pos = s - st;

        const f4* x4 = reinterpret_cast<const f4*>(tok + (size_t)row * DD);
        const f4 xv0 = x4[l0];
        const f4 xv1 = x4[l1];

        const f4* a4 = reinterpret_cast<const f4*>(add_tab + pos * DD);
        const f4 y0 = xv0 + a4[l0];
        const f4 y1 = xv1 + a4[l1];

        float sum = (y0.x + y0.y) + (y0.z + y0.w)
                  + (y1.x + y1.y) + (y1.z + y1.w);
        const f4 q0 = y0 * y0;
        const f4 q1 = y1 * y1;
        float sq = (q0.x + q0.y) + (q0.z + q0.w)
                 + (q1.x + q1.y) + (q1.z + q1.w);

        sum = wave_allreduce(sum, xaddr32);
        sq  = wave_allreduce(sq, xaddr32);

        const float mu  = sum * (1.0f / DD);
        const float var = sq * (1.0f / DD) - mu * mu;
        const float inv = rsqrtf(var + LN_EPS);

        f4* o4 = reinterpret_cast<f4*>(out + (size_t)row * DD);
        o4[l0] = (y0 - mu) * inv * w0 + c0;
        o4[l1] = (y1 - mu) * inv * w1 + c1;
    }
}

extern "C" void kernel_launch(void* const* d_in, const int* in_sizes, int n_in,
                              void* d_out, int out_size, void* d_ws, size_t ws_size,
                              hipStream_t stream) {
    const float* tok       = (const float*)d_in[0];   // (B,S,D)
    const int*   mask      = (const int*)d_in[1];     // (B,S)
    const float* item_pos  = (const float*)d_in[2];   // (64,D)
    const float* layer_emb = (const float*)d_in[3];   // (3,D)
    const float* decay     = (const float*)d_in[4];   // (64,D)
    const float* lnw       = (const float*)d_in[5];   // (D,)
    const float* lnb       = (const float*)d_in[6];   // (D,)
    float* out = (float*)d_out;

    // workspace layout: [ add_tab: SS*DD floats ][ start: BB ints ]
    float* add_tab = (float*)d_ws;
    int* start = (int*)((char*)d_ws + (size_t)SS * DD * sizeof(float));

    zerofill_kernel<<<BB * 2, 256, 0, stream>>>(mask, start, out);
    prep_kernel<<<SS, 128, 0, stream>>>(item_pos, layer_emb, decay, add_tab);
    content_kernel<<<CONTENT_BLOCKS, 256, 0, stream>>>(tok, add_tab, lnw, lnb,
                                                       start, out);
}

// Round 9
// 148.923 us; speedup vs baseline: 1.0279x; 1.0279x over previous
//
#include <hip/hip_runtime.h>

typedef float f4 __attribute__((ext_vector_type(4)));

#define BB 1024
#define SS 192
#define DD 512
#define NUM_LAYERS 3
#define LN_EPS 1e-5f
#define NROWS (BB * SS)
#define NPAIRS (NROWS / 2)              // 98304
#define FUSED_BLOCKS 2048
#define NWAVES (FUSED_BLOCKS * 4)       // 8192
#define NITER (NPAIRS / NWAVES)         // 12

// Merged prep:
//  blocks [0, SS)      : add_tab[pos] = item_pos[pos/3] + layer[pos%3] + decay[pos/3]
//  blocks [SS, SS+256) : start[b] via ballot; start=SS if row has no content
__global__ __launch_bounds__(256) void prep_kernel(
    const int* __restrict__ mask,
    const float* __restrict__ item_pos,
    const float* __restrict__ layer_emb,
    const float* __restrict__ decay,
    float* __restrict__ add_tab,
    int* __restrict__ start)
{
    if (blockIdx.x < SS) {
        const int p = blockIdx.x;
        const int t = threadIdx.x;
        if (t < DD / 4) {
            const int item = p / NUM_LAYERS;
            const int layer = p - item * NUM_LAYERS;
            const f4 iv = reinterpret_cast<const f4*>(item_pos + item * DD)[t];
            const f4 lv = reinterpret_cast<const f4*>(layer_emb + layer * DD)[t];
            const f4 dv = reinterpret_cast<const f4*>(decay + item * DD)[t];
            reinterpret_cast<f4*>(add_tab + p * DD)[t] = iv + lv + dv;
        }
    } else {
        const int b = (blockIdx.x - SS) * 4 + (threadIdx.x >> 6);
        const int lane = threadIdx.x & 63;
        if (b < BB) {
            const int* m = mask + b * SS;
            const unsigned long long b0 = __ballot(m[lane] > 0);
            const unsigned long long b1 = __ballot(m[lane + 64] > 0);
            const unsigned long long b2 = __ballot(m[lane + 128] > 0);
            int idx;
            if (b0)      idx = __ffsll(b0) - 1;
            else if (b1) idx = 64 + __ffsll(b1) - 1;
            else if (b2) idx = 128 + __ffsll(b2) - 1;
            else         idx = SS;
            if (lane == 0) start[b] = idx;
        }
    }
}

template <int CTRL>
__device__ __forceinline__ float dpp_x(float v) {
    return __uint_as_float((unsigned)__builtin_amdgcn_update_dpp(
            0, (int)__float_as_uint(v), CTRL, 0xF, 0xF, true));
}
__device__ __forceinline__ float swz16(float v) {
    return __uint_as_float((unsigned)__builtin_amdgcn_ds_swizzle(
            (int)__float_as_uint(v), 0x401f));
}
__device__ __forceinline__ float bper32(float v, int xaddr32) {
    return __uint_as_float((unsigned)__builtin_amdgcn_ds_bpermute(
            xaddr32, (int)__float_as_uint(v)));
}

// 4 concurrent wave64 all-reduces: each level's 4 ops are independent (ILP),
// so the serial chain costs about the same as ONE allreduce.
__device__ __forceinline__ void wave_allreduce4(
    float& v0, float& v1, float& v2, float& v3, int xaddr32)
{
    v0 += dpp_x<0xB1>(v0);  v1 += dpp_x<0xB1>(v1);
    v2 += dpp_x<0xB1>(v2);  v3 += dpp_x<0xB1>(v3);    // xor1 (quad_perm 1,0,3,2)
    v0 += dpp_x<0x4E>(v0);  v1 += dpp_x<0x4E>(v1);
    v2 += dpp_x<0x4E>(v2);  v3 += dpp_x<0x4E>(v3);    // xor2 (quad_perm 2,3,0,1)
    v0 += dpp_x<0x141>(v0); v1 += dpp_x<0x141>(v1);
    v2 += dpp_x<0x141>(v2); v3 += dpp_x<0x141>(v3);   // row_half_mirror
    v0 += dpp_x<0x140>(v0); v1 += dpp_x<0x140>(v1);
    v2 += dpp_x<0x140>(v2); v3 += dpp_x<0x140>(v3);   // row_mirror
    v0 += swz16(v0); v1 += swz16(v1); v2 += swz16(v2); v3 += swz16(v3);
    v0 += bper32(v0, xaddr32); v1 += bper32(v1, xaddr32);
    v2 += bper32(v2, xaddr32); v3 += bper32(v3, xaddr32);
}

// One wave per ADJACENT ROW PAIR (same b, s = 2j, 2j+1): 4KB contiguous token
// reads, 4KB contiguous stores, 2x in-flight bytes per wave, one start[b] load
// per pair, interleaved reduce chains. Stores are unconditional (zero-selected
// for padded rows); only loads sit behind wave-uniform branches.
__global__ __launch_bounds__(256) void fused_kernel(
    const float* __restrict__ tok,
    const float* __restrict__ add_tab,
    const float* __restrict__ lnw,
    const float* __restrict__ lnb,
    const int* __restrict__ start,
    float* __restrict__ out)
{
    const int wid = threadIdx.x >> 6;
    const int lane = threadIdx.x & 63;
    const int l0 = lane;
    const int l1 = lane + 64;
    const int xaddr32 = (lane ^ 32) << 2;

    const f4 w0 = reinterpret_cast<const f4*>(lnw)[l0];
    const f4 w1 = reinterpret_cast<const f4*>(lnw)[l1];
    const f4 c0 = reinterpret_cast<const f4*>(lnb)[l0];
    const f4 c1 = reinterpret_cast<const f4*>(lnb)[l1];

    const int wave = blockIdx.x * 4 + wid;
    const f4 z = {0.f, 0.f, 0.f, 0.f};

    #pragma unroll 1
    for (int p = wave; p < NPAIRS; p += NWAVES) {
        const int b = p / (SS / 2);
        const int jj = p - b * (SS / 2);
        const int s0 = jj * 2;                   // rows s0, s0+1 of batch b
        const int st = start[b];
        const bool k0 = (s0 >= st);
        const bool k1 = (s0 + 1 >= st);

        const size_t rbase = ((size_t)b * SS + s0) * DD;

        f4 x00 = z, x01 = z, x10 = z, x11 = z;
        f4 a00 = z, a01 = z, a10 = z, a11 = z;

        // issue all loads back-to-back (wave-uniform predicates)
        if (k0) {
            const f4* x4 = reinterpret_cast<const f4*>(tok + rbase);
            const f4* a4 = reinterpret_cast<const f4*>(add_tab + (s0 - st) * DD);
            x00 = x4[l0]; x01 = x4[l1];
            a00 = a4[l0]; a01 = a4[l1];
        }
        if (k1) {
            const f4* x4 = reinterpret_cast<const f4*>(tok + rbase) + DD / 4;
            const f4* a4 = reinterpret_cast<const f4*>(add_tab + (s0 + 1 - st) * DD);
            x10 = x4[l0]; x11 = x4[l1];
            a10 = a4[l0]; a11 = a4[l1];
        }

        const f4 y00 = x00 + a00, y01 = x01 + a01;   // row 0
        const f4 y10 = x10 + a10, y11 = x11 + a11;   // row 1

        float sumA = (y00.x + y00.y) + (y00.z + y00.w)
                   + (y01.x + y01.y) + (y01.z + y01.w);
        const f4 qa0 = y00 * y00, qa1 = y01 * y01;
        float sqA = (qa0.x + qa0.y) + (qa0.z + qa0.w)
                  + (qa1.x + qa1.y) + (qa1.z + qa1.w);

        float sumB = (y10.x + y10.y) + (y10.z + y10.w)
                   + (y11.x + y11.y) + (y11.z + y11.w);
        const f4 qb0 = y10 * y10, qb1 = y11 * y11;
        float sqB = (qb0.x + qb0.y) + (qb0.z + qb0.w)
                  + (qb1.x + qb1.y) + (qb1.z + qb1.w);

        wave_allreduce4(sumA, sqA, sumB, sqB, xaddr32);

        const float muA  = sumA * (1.0f / DD);
        const float varA = sqA * (1.0f / DD) - muA * muA;
        const float invA = rsqrtf(varA + LN_EPS);
        const float muB  = sumB * (1.0f / DD);
        const float varB = sqB * (1.0f / DD) - muB * muB;
        const float invB = rsqrtf(varB + LN_EPS);

        f4 o00 = (y00 - muA) * invA * w0 + c0;
        f4 o01 = (y01 - muA) * invA * w1 + c1;
        f4 o10 = (y10 - muB) * invB * w0 + c0;
        f4 o11 = (y11 - muB) * invB * w1 + c1;

        if (!k0) { o00 = z; o01 = z; }
        if (!k1) { o10 = z; o11 = z; }

        f4* ob = reinterpret_cast<f4*>(out + rbase);
        ob[l0] = o00;
        ob[l1] = o01;
        ob[l0 + DD / 4] = o10;
        ob[l1 + DD / 4] = o11;
    }
}

extern "C" void kernel_launch(void* const* d_in, const int* in_sizes, int n_in,
                              void* d_out, int out_size, void* d_ws, size_t ws_size,
                              hipStream_t stream) {
    const float* tok       = (const float*)d_in[0];   // (B,S,D)
    const int*   mask      = (const int*)d_in[1];     // (B,S)
    const float* item_pos  = (const float*)d_in[2];   // (64,D)
    const float* layer_emb = (const float*)d_in[3];   // (3,D)
    const float* decay     = (const float*)d_in[4];   // (64,D)
    const float* lnw       = (const float*)d_in[5];   // (D,)
    const float* lnb       = (const float*)d_in[6];   // (D,)
    float* out = (float*)d_out;

    // workspace layout: [ add_tab: SS*DD floats ][ start: BB ints ]
    float* add_tab = (float*)d_ws;
    int* start = (int*)((char*)d_ws + (size_t)SS * DD * sizeof(float));

    prep_kernel<<<SS + 256, 256, 0, stream>>>(mask, item_pos, layer_emb, decay,
                                              add_tab, start);
    fused_kernel<<<FUSED_BLOCKS, 256, 0, stream>>>(tok, add_tab, lnw, lnb, start, out);
}